// Round 4
// baseline (626.136 us; speedup 1.0000x reference)
//
#include <hip/hip_runtime.h>
#include <cstdint>
#include <cstddef>

#define NN 50000
#define NE 800000

typedef _Float16 f16x8 __attribute__((ext_vector_type(8)));
typedef _Float16 f16x4 __attribute__((ext_vector_type(4)));
typedef _Float16 f16x2 __attribute__((ext_vector_type(2)));
typedef float f32x4 __attribute__((ext_vector_type(4)));

// ---------------------------------------------------------------------------
// Edge-index dtype robustness (int64 vs int32 canonicalization)
// ---------------------------------------------------------------------------
__device__ __forceinline__ int edge_at(const void* e, int is32, long long i) {
    return is32 ? ((const int*)e)[i] : (int)((const long long*)e)[i];
}

__global__ __launch_bounds__(64) void zero_flag_k(int* flag) {
    if (threadIdx.x == 0) *flag = 0;
}

__global__ __launch_bounds__(256) void detect_k(const int* __restrict__ w, int* __restrict__ flag) {
    int i = blockIdx.x * 256 + threadIdx.x;   // 0..1023
    if (i < 1024 && w[2 * i + 1] != 0) atomicOr(flag, 1);
}

// ---------------------------------------------------------------------------
// Hadamard: X0 = qe*obj, written as fp16 hi/lo split pair
// ---------------------------------------------------------------------------
__global__ __launch_bounds__(256) void hadamard_k(const float4* __restrict__ a,
                                                  const float4* __restrict__ b,
                                                  _Float16* __restrict__ Xh,
                                                  _Float16* __restrict__ Xl, int n4) {
    int i = blockIdx.x * 256 + threadIdx.x;
    if (i >= n4) return;
    float4 x = a[i], y = b[i];
    float v[4] = { x.x * y.x, x.y * y.y, x.z * y.z, x.w * y.w };
    f16x4 hh, ll;
    #pragma unroll
    for (int j = 0; j < 4; ++j) {
        _Float16 h = (_Float16)v[j];
        hh[j] = h;
        ll[j] = (_Float16)(v[j] - (float)h);
    }
    *(f16x4*)&Xh[(size_t)i * 4] = hh;
    *(f16x4*)&Xl[(size_t)i * 4] = ll;
}

// ---------------------------------------------------------------------------
// Degree / CSR build
// ---------------------------------------------------------------------------
__global__ __launch_bounds__(256) void init_k(int* __restrict__ deg, int* __restrict__ cursor, int n) {
    int i = blockIdx.x * 256 + threadIdx.x;
    if (i < n) { deg[i] = 1; cursor[i] = 0; }   // self-loop
}

__global__ __launch_bounds__(256) void count_k(const void* __restrict__ edges,
                                               const int* __restrict__ flag,
                                               int* __restrict__ deg, int e) {
    int i = blockIdx.x * 256 + threadIdx.x;
    if (i < e) {
        int is32 = *flag;
        atomicAdd(&deg[edge_at(edges, is32, i)], 1);
    }
}

__global__ __launch_bounds__(256) void dinv_k(const int* __restrict__ deg, float* __restrict__ dinv, int n) {
    int i = blockIdx.x * 256 + threadIdx.x;
    if (i < n) dinv[i] = rsqrtf((float)deg[i]);
}

__global__ __launch_bounds__(1024) void scan_k(const int* __restrict__ deg, int* __restrict__ rp, int n) {
    __shared__ int s[1024];
    int t = threadIdx.x;
    int chunk = (n + 1023) / 1024;
    int lo = t * chunk;
    int hi = lo + chunk; if (hi > n) hi = n;
    int sum = 0;
    for (int i = lo; i < hi; ++i) sum += deg[i] - 1;
    s[t] = sum;
    __syncthreads();
    for (int off = 1; off < 1024; off <<= 1) {
        int val = (t >= off) ? s[t - off] : 0;
        __syncthreads();
        s[t] += val;
        __syncthreads();
    }
    int run = (t == 0) ? 0 : s[t - 1];
    for (int i = lo; i < hi; ++i) { rp[i] = run; run += deg[i] - 1; }
    if (t == 1023) rp[n] = s[1023];
}

// norm is recomputed in the aggregate from dinv (dinv is L2-resident, 200 KB);
// CSR stores column indices only -> 8x slice re-read costs 3.4 MB not 6.8 MB.
__global__ __launch_bounds__(256) void scatter_k(const void* __restrict__ edges,
                                                 const int* __restrict__ flag,
                                                 const int* __restrict__ rp,
                                                 int* __restrict__ cursor,
                                                 int* __restrict__ col_s, int e) {
    int i = blockIdx.x * 256 + threadIdx.x;
    if (i < e) {
        int is32 = *flag;
        int r = edge_at(edges, is32, i);
        int c = edge_at(edges, is32, (long long)NE + i);
        int pos = rp[r] + atomicAdd(&cursor[r], 1);
        col_s[pos] = c;
    }
}

// ---------------------------------------------------------------------------
// W convert: W[K=256][Nout] fp32 -> B3 [Nout][768] fp16, layout [Wh | Wl | Wh]
// so that A3=[Ah|Ah|Al] x B3=[Bh;Bl;Bh] = Ah*Bh + Ah*Bl + Al*Bh.
// ---------------------------------------------------------------------------
__global__ __launch_bounds__(256) void wconv3_k(const float* __restrict__ W,
                                                _Float16* __restrict__ B3, int Nout) {
    int n = blockIdx.x;            // 0..Nout-1
    int k = threadIdx.x;           // 0..255
    float v = W[(size_t)k * Nout + n];
    _Float16 h = (_Float16)v;
    _Float16 l = (_Float16)(v - (float)h);
    B3[(size_t)n * 768 + k]       = h;
    B3[(size_t)n * 768 + 256 + k] = l;
    B3[(size_t)n * 768 + 512 + k] = h;
}

// ---------------------------------------------------------------------------
// Single-pass fp16 MFMA GEMM over virtual K=768 (m97 structure).
// NBX=2: 1D grid of 800 with pair-swizzle so both N-blocks of a row panel land
// on the SAME XCD (A-panel fetched once per XCD). NBX=1: direct 1D grid.
// ---------------------------------------------------------------------------
__device__ __forceinline__ void gload_lds16(const void* g, void* l) {
    __builtin_amdgcn_global_load_lds(
        (const __attribute__((address_space(1))) void*)g,
        (__attribute__((address_space(3))) void*)l, 16, 0, 0);
}

template <int NBX>
__global__ __launch_bounds__(256) void gemm_f16_k(const _Float16* __restrict__ Ah,
                                                  const _Float16* __restrict__ Al,
                                                  const _Float16* __restrict__ B3,
                                                  float* __restrict__ C,
                                                  int M, int Nout) {
    __shared__ alignas(16) _Float16 sA[128 * 32];   // linear: row r at r*32, 64B rows
    __shared__ alignas(16) _Float16 sB[128 * 32];
    const int K1 = 256;
    int mblk = (M + 127) >> 7;

    int pair, xb;
    if (NBX == 2) {
        int b = blockIdx.x;
        pair = (b >> 4) * 8 + (b & 7);     // row-panel id; pinned to XCD (b&7)
        xb   = (b >> 3) & 1;
        if (pair >= mblk) return;
    } else {
        pair = blockIdx.x;
        xb = 0;
    }

    int tid = threadIdx.x;
    int row0 = pair * 128, col0 = xb * 128;
    int wid = tid >> 6, lane = tid & 63;
    int wm = wid >> 1, wn = wid & 1;
    int fr = lane & 15;
    int kb = (lane >> 4) * 8;       // k element base within 32

    int sr = lane >> 2;
    int ke = (lane & 3) * 8;

    f32x4 acc[4][4] = {};

    for (int s = 0; s < 24; ++s) {
        int seg = s >> 3;                 // 0: Ah, 1: Ah (L2-hot), 2: Al
        int k0 = (s & 7) * 32;
        const _Float16* Asrc = (seg == 2) ? Al : Ah;

        __syncthreads();                  // LDS reuse: prior reads done
        #pragma unroll
        for (int c = 0; c < 2; ++c) {
            int ch = wid * 2 + c;         // 0..7
            int r = ch * 16 + sr;
            int arow = row0 + r;
            if (arow < M)
                gload_lds16(&Asrc[(size_t)arow * K1 + k0 + ke], &sA[ch * 512]);
            gload_lds16(&B3[(size_t)(col0 + r) * 768 + s * 32 + ke], &sB[ch * 512]);
        }
        __syncthreads();                  // drains vmcnt (global_load_lds) too

        f16x8 af[4];
        #pragma unroll
        for (int f = 0; f < 4; ++f)
            af[f] = *(const f16x8*)&sA[(wm * 64 + f * 16 + fr) * 32 + kb];
        #pragma unroll
        for (int g = 0; g < 4; ++g) {
            f16x8 bf_ = *(const f16x8*)&sB[(wn * 64 + g * 16 + fr) * 32 + kb];
            #pragma unroll
            for (int f = 0; f < 4; ++f)
                acc[f][g] = __builtin_amdgcn_mfma_f32_16x16x32_f16(af[f], bf_, acc[f][g], 0, 0, 0);
        }
    }

    int rsub = (lane >> 4) * 4;
    #pragma unroll
    for (int f = 0; f < 4; ++f) {
        #pragma unroll
        for (int g = 0; g < 4; ++g) {
            int col = col0 + wn * 64 + g * 16 + fr;
            #pragma unroll
            for (int r = 0; r < 4; ++r) {
                int row = row0 + wm * 64 + f * 16 + rsub + r;
                if (row < M) C[(size_t)row * Nout + col] = acc[f][g][r];
            }
        }
    }
}

// ---------------------------------------------------------------------------
// XCD-sliced aggregation. Block bid handles destination-node chunk (bid>>3)
// for column slice (bid&7). Consecutive blockIdx round-robin across the 8
// XCDs, so slice s is processed only on XCD s: per-XCD H working set drops
// 51.2 MB -> 6.4 MB (D=256 slice = 32 cols = one 128B L2 line per row).
// norm = dinv[v]*dinv[c] recomputed (dinv L2-resident everywhere).
// MODE 0: relu, write fp16 hi/lo split; MODE 1: write fp32.
// ---------------------------------------------------------------------------
template <int D, int MODE>
__global__ __launch_bounds__(256) void aggregate_slice_k(const float* __restrict__ H,
                                                         const float* __restrict__ bias,
                                                         const float* __restrict__ dinv,
                                                         const int* __restrict__ rp,
                                                         const int* __restrict__ cs,
                                                         _Float16* __restrict__ Yh,
                                                         _Float16* __restrict__ Yl,
                                                         float* __restrict__ Yf, int n) {
    constexpr int SLICE = (D == 256) ? 32 : 16;   // cols per slice
    constexpr int LPN = SLICE / 2;                // lanes per node (float2 each)
    constexpr int NPB = 256 / LPN;                // nodes per block

    int bid = blockIdx.x;
    int s = bid & 7;
    int v = (bid >> 3) * NPB + threadIdx.x / LPN;
    if (v >= n) return;
    int sub = threadIdx.x % LPN;
    int col = s * SLICE + sub * 2;

    float dv = dinv[v];
    float self = dv * dv;
    float2 t0 = *(const float2*)&H[(size_t)v * D + col];
    float ax = self * t0.x, ay = self * t0.y;

    int beg = rp[v], end = rp[v + 1];
    int j = beg;
    for (; j + 4 <= end; j += 4) {
        int c0 = cs[j], c1 = cs[j + 1], c2 = cs[j + 2], c3 = cs[j + 3];
        float n0 = dv * dinv[c0], n1 = dv * dinv[c1];
        float n2 = dv * dinv[c2], n3 = dv * dinv[c3];
        float2 a = *(const float2*)&H[(size_t)c0 * D + col];
        float2 b = *(const float2*)&H[(size_t)c1 * D + col];
        float2 c = *(const float2*)&H[(size_t)c2 * D + col];
        float2 d = *(const float2*)&H[(size_t)c3 * D + col];
        ax += n0 * a.x + n1 * b.x + n2 * c.x + n3 * d.x;
        ay += n0 * a.y + n1 * b.y + n2 * c.y + n3 * d.y;
    }
    for (; j < end; ++j) {
        int c = cs[j];
        float nm = dv * dinv[c];
        float2 a = *(const float2*)&H[(size_t)c * D + col];
        ax += nm * a.x;
        ay += nm * a.y;
    }

    float2 bb = *(const float2*)&bias[col];
    ax += bb.x;
    ay += bb.y;

    if constexpr (MODE == 0) {
        float ox = fmaxf(ax, 0.0f), oy = fmaxf(ay, 0.0f);
        _Float16 hx = (_Float16)ox, hy = (_Float16)oy;
        f16x2 hh, ll;
        hh[0] = hx; hh[1] = hy;
        ll[0] = (_Float16)(ox - (float)hx);
        ll[1] = (_Float16)(oy - (float)hy);
        *(f16x2*)&Yh[(size_t)v * D + col] = hh;
        *(f16x2*)&Yl[(size_t)v * D + col] = ll;
    } else {
        *(float2*)&Yf[(size_t)v * D + col] = make_float2(ax, ay);
    }
}

// ---------------------------------------------------------------------------
extern "C" void kernel_launch(void* const* d_in, const int* in_sizes, int n_in,
                              void* d_out, int out_size, void* d_ws, size_t ws_size,
                              hipStream_t stream) {
    const float* qe  = (const float*)d_in[0];
    const float* obj = (const float*)d_in[1];
    const void*  edges = d_in[2];
    const float* W1 = (const float*)d_in[3];
    const float* b1 = (const float*)d_in[4];
    const float* W2 = (const float*)d_in[5];
    const float* b2 = (const float*)d_in[6];
    const float* W3 = (const float*)d_in[7];
    const float* b3 = (const float*)d_in[8];
    float* out = (float*)d_out;

    char* p = (char*)d_ws;
    _Float16* Xh   = (_Float16*)p; p += (size_t)NN * 256 * 2;   // 25.6 MB
    _Float16* Xl   = (_Float16*)p; p += (size_t)NN * 256 * 2;   // 25.6 MB
    float* H       = (float*)p;    p += (size_t)NN * 256 * 4;   // 51.2 MB
    _Float16* B3   = (_Float16*)p; p += (size_t)256 * 768 * 2;  // 0.4 MB
    int*   deg     = (int*)p;   p += (size_t)NN * 4;
    float* dinv    = (float*)p; p += (size_t)NN * 4;
    int*   rp      = (int*)p;   p += (size_t)(NN + 1) * 4;
    int*   cursor  = (int*)p;   p += (size_t)NN * 4;
    int*   col_s   = (int*)p;   p += (size_t)NE * 4;
    int*   flag    = (int*)p;   p += 4;

    zero_flag_k<<<1, 64, 0, stream>>>(flag);
    detect_k<<<4, 256, 0, stream>>>((const int*)edges, flag);
    hadamard_k<<<(NN * 64 + 255) / 256, 256, 0, stream>>>(
        (const float4*)qe, (const float4*)obj, Xh, Xl, NN * 64);
    init_k<<<(NN + 255) / 256, 256, 0, stream>>>(deg, cursor, NN);
    count_k<<<(NE + 255) / 256, 256, 0, stream>>>(edges, flag, deg, NE);
    dinv_k<<<(NN + 255) / 256, 256, 0, stream>>>(deg, dinv, NN);
    scan_k<<<1, 1024, 0, stream>>>(deg, rp, NN);
    scatter_k<<<(NE + 255) / 256, 256, 0, stream>>>(edges, flag, rp, cursor, col_s, NE);

    int mblk = (NN + 127) / 128;                 // 391
    int gemmBigGrid = ((mblk + 7) / 8) * 16;     // 800 (pair-swizzled, 2 col blocks)
    int agg256Grid = ((NN + 15) / 16) * 8;       // 25000
    int agg128Grid = ((NN + 31) / 32) * 8;       // 12504

    // Layer 1
    wconv3_k<<<256, 256, 0, stream>>>(W1, B3, 256);
    gemm_f16_k<2><<<gemmBigGrid, 256, 0, stream>>>(Xh, Xl, B3, H, NN, 256);
    aggregate_slice_k<256, 0><<<agg256Grid, 256, 0, stream>>>(H, b1, dinv, rp, col_s,
                                                              Xh, Xl, nullptr, NN);
    // Layer 2
    wconv3_k<<<256, 256, 0, stream>>>(W2, B3, 256);
    gemm_f16_k<2><<<gemmBigGrid, 256, 0, stream>>>(Xh, Xl, B3, H, NN, 256);
    aggregate_slice_k<256, 0><<<agg256Grid, 256, 0, stream>>>(H, b2, dinv, rp, col_s,
                                                              Xh, Xl, nullptr, NN);
    // Layer 3
    wconv3_k<<<128, 256, 0, stream>>>(W3, B3, 128);
    gemm_f16_k<1><<<mblk, 256, 0, stream>>>(Xh, Xl, B3, H, NN, 128);
    aggregate_slice_k<128, 1><<<agg128Grid, 256, 0, stream>>>(H, b3, dinv, rp, col_s,
                                                              nullptr, nullptr, out, NN);
}

// Round 5
// 599.479 us; speedup vs baseline: 1.0445x; 1.0445x over previous
//
#include <hip/hip_runtime.h>
#include <cstdint>
#include <cstddef>

#define NN 50000
#define NE 800000

typedef _Float16 f16x8 __attribute__((ext_vector_type(8)));
typedef _Float16 f16x4 __attribute__((ext_vector_type(4)));
typedef _Float16 f16x2 __attribute__((ext_vector_type(2)));
typedef float f32x4 __attribute__((ext_vector_type(4)));

// ---------------------------------------------------------------------------
// Edge-index dtype robustness (int64 vs int32 canonicalization)
// ---------------------------------------------------------------------------
__device__ __forceinline__ int edge_at(const void* e, int is32, long long i) {
    return is32 ? ((const int*)e)[i] : (int)((const long long*)e)[i];
}

__global__ __launch_bounds__(64) void zero_flag_k(int* flag) {
    if (threadIdx.x == 0) *flag = 0;
}

__global__ __launch_bounds__(256) void detect_k(const int* __restrict__ w, int* __restrict__ flag) {
    int i = blockIdx.x * 256 + threadIdx.x;   // 0..1023
    if (i < 1024 && w[2 * i + 1] != 0) atomicOr(flag, 1);
}

// ---------------------------------------------------------------------------
// Hadamard: X0 = qe*obj, written as fp16 hi/lo split pair
// ---------------------------------------------------------------------------
__global__ __launch_bounds__(256) void hadamard_k(const float4* __restrict__ a,
                                                  const float4* __restrict__ b,
                                                  _Float16* __restrict__ Xh,
                                                  _Float16* __restrict__ Xl, int n4) {
    int i = blockIdx.x * 256 + threadIdx.x;
    if (i >= n4) return;
    float4 x = a[i], y = b[i];
    float v[4] = { x.x * y.x, x.y * y.y, x.z * y.z, x.w * y.w };
    f16x4 hh, ll;
    #pragma unroll
    for (int j = 0; j < 4; ++j) {
        _Float16 h = (_Float16)v[j];
        hh[j] = h;
        ll[j] = (_Float16)(v[j] - (float)h);
    }
    *(f16x4*)&Xh[(size_t)i * 4] = hh;
    *(f16x4*)&Xl[(size_t)i * 4] = ll;
}

// ---------------------------------------------------------------------------
// Degree / CSR build
// ---------------------------------------------------------------------------
__global__ __launch_bounds__(256) void init_k(int* __restrict__ deg, int* __restrict__ cursor, int n) {
    int i = blockIdx.x * 256 + threadIdx.x;
    if (i < n) { deg[i] = 1; cursor[i] = 0; }   // self-loop
}

__global__ __launch_bounds__(256) void count_k(const void* __restrict__ edges,
                                               const int* __restrict__ flag,
                                               int* __restrict__ deg, int e) {
    int i = blockIdx.x * 256 + threadIdx.x;
    if (i < e) {
        int is32 = *flag;
        atomicAdd(&deg[edge_at(edges, is32, i)], 1);
    }
}

__global__ __launch_bounds__(256) void dinv_k(const int* __restrict__ deg, float* __restrict__ dinv, int n) {
    int i = blockIdx.x * 256 + threadIdx.x;
    if (i < n) dinv[i] = rsqrtf((float)deg[i]);
}

__global__ __launch_bounds__(1024) void scan_k(const int* __restrict__ deg, int* __restrict__ rp, int n) {
    __shared__ int s[1024];
    int t = threadIdx.x;
    int chunk = (n + 1023) / 1024;
    int lo = t * chunk;
    int hi = lo + chunk; if (hi > n) hi = n;
    int sum = 0;
    for (int i = lo; i < hi; ++i) sum += deg[i] - 1;
    s[t] = sum;
    __syncthreads();
    for (int off = 1; off < 1024; off <<= 1) {
        int val = (t >= off) ? s[t - off] : 0;
        __syncthreads();
        s[t] += val;
        __syncthreads();
    }
    int run = (t == 0) ? 0 : s[t - 1];
    for (int i = lo; i < hi; ++i) { rp[i] = run; run += deg[i] - 1; }
    if (t == 1023) rp[n] = s[1023];
}

// norm recomputed in the aggregate from dinv (L2-resident); CSR stores cols only.
__global__ __launch_bounds__(256) void scatter_k(const void* __restrict__ edges,
                                                 const int* __restrict__ flag,
                                                 const int* __restrict__ rp,
                                                 int* __restrict__ cursor,
                                                 int* __restrict__ col_s, int e) {
    int i = blockIdx.x * 256 + threadIdx.x;
    if (i < e) {
        int is32 = *flag;
        int r = edge_at(edges, is32, i);
        int c = edge_at(edges, is32, (long long)NE + i);
        int pos = rp[r] + atomicAdd(&cursor[r], 1);
        col_s[pos] = c;
    }
}

// ---------------------------------------------------------------------------
// W convert: W[K=256][Nout] fp32 -> B3 [Nout][768] fp16, layout [Wh | Wl | Wh]
// ---------------------------------------------------------------------------
__global__ __launch_bounds__(256) void wconv3_k(const float* __restrict__ W,
                                                _Float16* __restrict__ B3, int Nout) {
    int n = blockIdx.x;            // 0..Nout-1
    int k = threadIdx.x;           // 0..255
    float v = W[(size_t)k * Nout + n];
    _Float16 h = (_Float16)v;
    _Float16 l = (_Float16)(v - (float)h);
    B3[(size_t)n * 768 + k]       = h;
    B3[(size_t)n * 768 + 256 + k] = l;
    B3[(size_t)n * 768 + 512 + k] = h;
}

// ---------------------------------------------------------------------------
// Single-pass fp16 MFMA GEMM over virtual K=768 (m97 structure).
// ---------------------------------------------------------------------------
__device__ __forceinline__ void gload_lds16(const void* g, void* l) {
    __builtin_amdgcn_global_load_lds(
        (const __attribute__((address_space(1))) void*)g,
        (__attribute__((address_space(3))) void*)l, 16, 0, 0);
}

template <int NBX>
__global__ __launch_bounds__(256) void gemm_f16_k(const _Float16* __restrict__ Ah,
                                                  const _Float16* __restrict__ Al,
                                                  const _Float16* __restrict__ B3,
                                                  float* __restrict__ C,
                                                  int M, int Nout) {
    __shared__ alignas(16) _Float16 sA[128 * 32];   // linear: row r at r*32, 64B rows
    __shared__ alignas(16) _Float16 sB[128 * 32];
    const int K1 = 256;
    int mblk = (M + 127) >> 7;

    int pair, xb;
    if (NBX == 2) {
        int b = blockIdx.x;
        pair = (b >> 4) * 8 + (b & 7);     // row-panel id; pinned to XCD (b&7)
        xb   = (b >> 3) & 1;
        if (pair >= mblk) return;
    } else {
        pair = blockIdx.x;
        xb = 0;
    }

    int tid = threadIdx.x;
    int row0 = pair * 128, col0 = xb * 128;
    int wid = tid >> 6, lane = tid & 63;
    int wm = wid >> 1, wn = wid & 1;
    int fr = lane & 15;
    int kb = (lane >> 4) * 8;       // k element base within 32

    int sr = lane >> 2;
    int ke = (lane & 3) * 8;

    f32x4 acc[4][4] = {};

    for (int s = 0; s < 24; ++s) {
        int seg = s >> 3;                 // 0: Ah, 1: Ah (L2-hot), 2: Al
        int k0 = (s & 7) * 32;
        const _Float16* Asrc = (seg == 2) ? Al : Ah;

        __syncthreads();                  // LDS reuse: prior reads done
        #pragma unroll
        for (int c = 0; c < 2; ++c) {
            int ch = wid * 2 + c;         // 0..7
            int r = ch * 16 + sr;
            int arow = row0 + r;
            if (arow < M)
                gload_lds16(&Asrc[(size_t)arow * K1 + k0 + ke], &sA[ch * 512]);
            gload_lds16(&B3[(size_t)(col0 + r) * 768 + s * 32 + ke], &sB[ch * 512]);
        }
        __syncthreads();                  // drains vmcnt (global_load_lds) too

        f16x8 af[4];
        #pragma unroll
        for (int f = 0; f < 4; ++f)
            af[f] = *(const f16x8*)&sA[(wm * 64 + f * 16 + fr) * 32 + kb];
        #pragma unroll
        for (int g = 0; g < 4; ++g) {
            f16x8 bf_ = *(const f16x8*)&sB[(wn * 64 + g * 16 + fr) * 32 + kb];
            #pragma unroll
            for (int f = 0; f < 4; ++f)
                acc[f][g] = __builtin_amdgcn_mfma_f32_16x16x32_f16(af[f], bf_, acc[f][g], 0, 0, 0);
        }
    }

    int rsub = (lane >> 4) * 4;
    #pragma unroll
    for (int f = 0; f < 4; ++f) {
        #pragma unroll
        for (int g = 0; g < 4; ++g) {
            int col = col0 + wn * 64 + g * 16 + fr;
            #pragma unroll
            for (int r = 0; r < 4; ++r) {
                int row = row0 + wm * 64 + f * 16 + rsub + r;
                if (row < M) C[(size_t)row * Nout + col] = acc[f][g][r];
            }
        }
    }
}

// ---------------------------------------------------------------------------
// XCD-sliced aggregation v3: 8 lanes x float4 per node (32-col slice),
// 8 nodes/wave, 32 nodes/block -> ~4x fewer instructions per edge-visit
// than the 16-lane float2 version. slice = bid&7 pins slice->XCD.
// D=128: SLICE=16 (4 lanes x float4), per-XCD working set 3.2 MB (L2-fits).
// ---------------------------------------------------------------------------
template <int D, int MODE>
__global__ __launch_bounds__(256) void aggregate_slice_k(const float* __restrict__ H,
                                                         const float* __restrict__ bias,
                                                         const float* __restrict__ dinv,
                                                         const int* __restrict__ rp,
                                                         const int* __restrict__ cs,
                                                         _Float16* __restrict__ Yh,
                                                         _Float16* __restrict__ Yl,
                                                         float* __restrict__ Yf, int n) {
    constexpr int SLICE = (D == 256) ? 32 : 16;   // cols per slice
    constexpr int LPN = SLICE / 4;                // lanes per node (float4 each)
    constexpr int NPB = 256 / LPN;                // nodes per block

    int bid = blockIdx.x;
    int s = bid & 7;
    int v = (bid >> 3) * NPB + threadIdx.x / LPN;
    if (v >= n) return;
    int sub = threadIdx.x % LPN;
    int col = s * SLICE + sub * 4;

    float dv = dinv[v];
    float self = dv * dv;
    float4 t0 = *(const float4*)&H[(size_t)v * D + col];
    float ax = self * t0.x, ay = self * t0.y, az = self * t0.z, aw = self * t0.w;

    int beg = rp[v], end = rp[v + 1];
    int j = beg;
    for (; j + 4 <= end; j += 4) {
        int c0 = cs[j], c1 = cs[j + 1], c2 = cs[j + 2], c3 = cs[j + 3];
        float n0 = dv * dinv[c0], n1 = dv * dinv[c1];
        float n2 = dv * dinv[c2], n3 = dv * dinv[c3];
        float4 a = *(const float4*)&H[(size_t)c0 * D + col];
        float4 b = *(const float4*)&H[(size_t)c1 * D + col];
        float4 c = *(const float4*)&H[(size_t)c2 * D + col];
        float4 d = *(const float4*)&H[(size_t)c3 * D + col];
        ax += n0 * a.x + n1 * b.x + n2 * c.x + n3 * d.x;
        ay += n0 * a.y + n1 * b.y + n2 * c.y + n3 * d.y;
        az += n0 * a.z + n1 * b.z + n2 * c.z + n3 * d.z;
        aw += n0 * a.w + n1 * b.w + n2 * c.w + n3 * d.w;
    }
    for (; j < end; ++j) {
        int c = cs[j];
        float nm = dv * dinv[c];
        float4 a = *(const float4*)&H[(size_t)c * D + col];
        ax += nm * a.x; ay += nm * a.y; az += nm * a.z; aw += nm * a.w;
    }

    float4 bb = *(const float4*)&bias[col];
    ax += bb.x; ay += bb.y; az += bb.z; aw += bb.w;

    if constexpr (MODE == 0) {
        float o[4] = { fmaxf(ax, 0.0f), fmaxf(ay, 0.0f), fmaxf(az, 0.0f), fmaxf(aw, 0.0f) };
        f16x4 hh, ll;
        #pragma unroll
        for (int i = 0; i < 4; ++i) {
            _Float16 h = (_Float16)o[i];
            hh[i] = h;
            ll[i] = (_Float16)(o[i] - (float)h);
        }
        *(f16x4*)&Yh[(size_t)v * D + col] = hh;
        *(f16x4*)&Yl[(size_t)v * D + col] = ll;
    } else {
        *(float4*)&Yf[(size_t)v * D + col] = make_float4(ax, ay, az, aw);
    }
}

// ---------------------------------------------------------------------------
extern "C" void kernel_launch(void* const* d_in, const int* in_sizes, int n_in,
                              void* d_out, int out_size, void* d_ws, size_t ws_size,
                              hipStream_t stream) {
    const float* qe  = (const float*)d_in[0];
    const float* obj = (const float*)d_in[1];
    const void*  edges = d_in[2];
    const float* W1 = (const float*)d_in[3];
    const float* b1 = (const float*)d_in[4];
    const float* W2 = (const float*)d_in[5];
    const float* b2 = (const float*)d_in[6];
    const float* W3 = (const float*)d_in[7];
    const float* b3 = (const float*)d_in[8];
    float* out = (float*)d_out;

    char* p = (char*)d_ws;
    _Float16* Xh   = (_Float16*)p; p += (size_t)NN * 256 * 2;   // 25.6 MB
    _Float16* Xl   = (_Float16*)p; p += (size_t)NN * 256 * 2;   // 25.6 MB
    float* H       = (float*)p;    p += (size_t)NN * 256 * 4;   // 51.2 MB
    _Float16* B3   = (_Float16*)p; p += (size_t)256 * 768 * 2;  // 0.4 MB
    int*   deg     = (int*)p;   p += (size_t)NN * 4;
    float* dinv    = (float*)p; p += (size_t)NN * 4;
    int*   rp      = (int*)p;   p += (size_t)(NN + 1) * 4;
    int*   cursor  = (int*)p;   p += (size_t)NN * 4;
    int*   col_s   = (int*)p;   p += (size_t)NE * 4;
    int*   flag    = (int*)p;   p += 4;

    zero_flag_k<<<1, 64, 0, stream>>>(flag);
    detect_k<<<4, 256, 0, stream>>>((const int*)edges, flag);
    hadamard_k<<<(NN * 64 + 255) / 256, 256, 0, stream>>>(
        (const float4*)qe, (const float4*)obj, Xh, Xl, NN * 64);
    init_k<<<(NN + 255) / 256, 256, 0, stream>>>(deg, cursor, NN);
    count_k<<<(NE + 255) / 256, 256, 0, stream>>>(edges, flag, deg, NE);
    dinv_k<<<(NN + 255) / 256, 256, 0, stream>>>(deg, dinv, NN);
    scan_k<<<1, 1024, 0, stream>>>(deg, rp, NN);
    scatter_k<<<(NE + 255) / 256, 256, 0, stream>>>(edges, flag, rp, cursor, col_s, NE);

    int mblk = (NN + 127) / 128;                 // 391
    int gemmBigGrid = ((mblk + 7) / 8) * 16;     // 800 (pair-swizzled, 2 col blocks)
    int agg256Grid = ((NN + 31) / 32) * 8;       // 12504
    int agg128Grid = ((NN + 63) / 64) * 8;       // 6256

    // Layer 1
    wconv3_k<<<256, 256, 0, stream>>>(W1, B3, 256);
    gemm_f16_k<2><<<gemmBigGrid, 256, 0, stream>>>(Xh, Xl, B3, H, NN, 256);
    aggregate_slice_k<256, 0><<<agg256Grid, 256, 0, stream>>>(H, b1, dinv, rp, col_s,
                                                              Xh, Xl, nullptr, NN);
    // Layer 2
    wconv3_k<<<256, 256, 0, stream>>>(W2, B3, 256);
    gemm_f16_k<2><<<gemmBigGrid, 256, 0, stream>>>(Xh, Xl, B3, H, NN, 256);
    aggregate_slice_k<256, 0><<<agg256Grid, 256, 0, stream>>>(H, b2, dinv, rp, col_s,
                                                              Xh, Xl, nullptr, NN);
    // Layer 3
    wconv3_k<<<128, 256, 0, stream>>>(W3, B3, 128);
    gemm_f16_k<1><<<mblk, 256, 0, stream>>>(Xh, Xl, B3, H, NN, 128);
    aggregate_slice_k<128, 1><<<agg128Grid, 256, 0, stream>>>(H, b3, dinv, rp, col_s,
                                                              nullptr, nullptr, out, NN);
}

// Round 6
// 590.688 us; speedup vs baseline: 1.0600x; 1.0149x over previous
//
#include <hip/hip_runtime.h>
#include <cstdint>
#include <cstddef>

#define NN 50000
#define NE 800000

typedef _Float16 f16x8 __attribute__((ext_vector_type(8)));
typedef _Float16 f16x4 __attribute__((ext_vector_type(4)));
typedef _Float16 f16x2 __attribute__((ext_vector_type(2)));
typedef float f32x4 __attribute__((ext_vector_type(4)));

// ---------------------------------------------------------------------------
// Edge-index dtype robustness (int64 vs int32 canonicalization)
// ---------------------------------------------------------------------------
__device__ __forceinline__ int edge_at(const void* e, int is32, long long i) {
    return is32 ? ((const int*)e)[i] : (int)((const long long*)e)[i];
}

__global__ __launch_bounds__(64) void zero_flag_k(int* flag) {
    if (threadIdx.x == 0) *flag = 0;
}

__global__ __launch_bounds__(256) void detect_k(const int* __restrict__ w, int* __restrict__ flag) {
    int i = blockIdx.x * 256 + threadIdx.x;   // 0..1023
    if (i < 1024 && w[2 * i + 1] != 0) atomicOr(flag, 1);
}

// ---------------------------------------------------------------------------
// Hadamard: X0 = qe*obj, written as fp16 hi/lo split pair
// ---------------------------------------------------------------------------
__global__ __launch_bounds__(256) void hadamard_k(const float4* __restrict__ a,
                                                  const float4* __restrict__ b,
                                                  _Float16* __restrict__ Xh,
                                                  _Float16* __restrict__ Xl, int n4) {
    int i = blockIdx.x * 256 + threadIdx.x;
    if (i >= n4) return;
    float4 x = a[i], y = b[i];
    float v[4] = { x.x * y.x, x.y * y.y, x.z * y.z, x.w * y.w };
    f16x4 hh, ll;
    #pragma unroll
    for (int j = 0; j < 4; ++j) {
        _Float16 h = (_Float16)v[j];
        hh[j] = h;
        ll[j] = (_Float16)(v[j] - (float)h);
    }
    *(f16x4*)&Xh[(size_t)i * 4] = hh;
    *(f16x4*)&Xl[(size_t)i * 4] = ll;
}

// ---------------------------------------------------------------------------
// Degree / CSR build
// ---------------------------------------------------------------------------
__global__ __launch_bounds__(256) void init_k(int* __restrict__ deg, int* __restrict__ cursor, int n) {
    int i = blockIdx.x * 256 + threadIdx.x;
    if (i < n) { deg[i] = 1; cursor[i] = 0; }   // self-loop
}

__global__ __launch_bounds__(256) void count_k(const void* __restrict__ edges,
                                               const int* __restrict__ flag,
                                               int* __restrict__ deg, int e) {
    int i = blockIdx.x * 256 + threadIdx.x;
    if (i < e) {
        int is32 = *flag;
        atomicAdd(&deg[edge_at(edges, is32, i)], 1);
    }
}

__global__ __launch_bounds__(256) void dinv_k(const int* __restrict__ deg, float* __restrict__ dinv, int n) {
    int i = blockIdx.x * 256 + threadIdx.x;
    if (i < n) dinv[i] = rsqrtf((float)deg[i]);
}

__global__ __launch_bounds__(1024) void scan_k(const int* __restrict__ deg, int* __restrict__ rp, int n) {
    __shared__ int s[1024];
    int t = threadIdx.x;
    int chunk = (n + 1023) / 1024;
    int lo = t * chunk;
    int hi = lo + chunk; if (hi > n) hi = n;
    int sum = 0;
    for (int i = lo; i < hi; ++i) sum += deg[i] - 1;
    s[t] = sum;
    __syncthreads();
    for (int off = 1; off < 1024; off <<= 1) {
        int val = (t >= off) ? s[t - off] : 0;
        __syncthreads();
        s[t] += val;
        __syncthreads();
    }
    int run = (t == 0) ? 0 : s[t - 1];
    for (int i = lo; i < hi; ++i) { rp[i] = run; run += deg[i] - 1; }
    if (t == 1023) rp[n] = s[1023];
}

// norm recomputed in the aggregate from dinv (L2-resident); CSR stores cols only.
__global__ __launch_bounds__(256) void scatter_k(const void* __restrict__ edges,
                                                 const int* __restrict__ flag,
                                                 const int* __restrict__ rp,
                                                 int* __restrict__ cursor,
                                                 int* __restrict__ col_s, int e) {
    int i = blockIdx.x * 256 + threadIdx.x;
    if (i < e) {
        int is32 = *flag;
        int r = edge_at(edges, is32, i);
        int c = edge_at(edges, is32, (long long)NE + i);
        int pos = rp[r] + atomicAdd(&cursor[r], 1);
        col_s[pos] = c;
    }
}

// ---------------------------------------------------------------------------
// W convert: W[K=256][Nout] fp32 -> B3 [Nout][768] fp16, layout [Wh | Wl | Wh]
// ---------------------------------------------------------------------------
__global__ __launch_bounds__(256) void wconv3_k(const float* __restrict__ W,
                                                _Float16* __restrict__ B3, int Nout) {
    int n = blockIdx.x;            // 0..Nout-1
    int k = threadIdx.x;           // 0..255
    float v = W[(size_t)k * Nout + n];
    _Float16 h = (_Float16)v;
    _Float16 l = (_Float16)(v - (float)h);
    B3[(size_t)n * 768 + k]       = h;
    B3[(size_t)n * 768 + 256 + k] = l;
    B3[(size_t)n * 768 + 512 + k] = h;
}

// ---------------------------------------------------------------------------
// Single-pass fp16 MFMA GEMM over virtual K=768 (m97 structure).
// Output H is written as fp16 (feeds the gather-aggregate; fp16 rounding of H
// enters the error budget once per layer, ~1e-3).
// ---------------------------------------------------------------------------
__device__ __forceinline__ void gload_lds16(const void* g, void* l) {
    __builtin_amdgcn_global_load_lds(
        (const __attribute__((address_space(1))) void*)g,
        (__attribute__((address_space(3))) void*)l, 16, 0, 0);
}

template <int NBX>
__global__ __launch_bounds__(256) void gemm_f16_k(const _Float16* __restrict__ Ah,
                                                  const _Float16* __restrict__ Al,
                                                  const _Float16* __restrict__ B3,
                                                  _Float16* __restrict__ C,
                                                  int M, int Nout) {
    __shared__ alignas(16) _Float16 sA[128 * 32];   // linear: row r at r*32, 64B rows
    __shared__ alignas(16) _Float16 sB[128 * 32];
    const int K1 = 256;
    int mblk = (M + 127) >> 7;

    int pair, xb;
    if (NBX == 2) {
        int b = blockIdx.x;
        pair = (b >> 4) * 8 + (b & 7);     // row-panel id; pinned to XCD (b&7)
        xb   = (b >> 3) & 1;
        if (pair >= mblk) return;
    } else {
        pair = blockIdx.x;
        xb = 0;
    }

    int tid = threadIdx.x;
    int row0 = pair * 128, col0 = xb * 128;
    int wid = tid >> 6, lane = tid & 63;
    int wm = wid >> 1, wn = wid & 1;
    int fr = lane & 15;
    int kb = (lane >> 4) * 8;       // k element base within 32

    int sr = lane >> 2;
    int ke = (lane & 3) * 8;

    f32x4 acc[4][4] = {};

    for (int s = 0; s < 24; ++s) {
        int seg = s >> 3;                 // 0: Ah, 1: Ah (L2-hot), 2: Al
        int k0 = (s & 7) * 32;
        const _Float16* Asrc = (seg == 2) ? Al : Ah;

        __syncthreads();                  // LDS reuse: prior reads done
        #pragma unroll
        for (int c = 0; c < 2; ++c) {
            int ch = wid * 2 + c;         // 0..7
            int r = ch * 16 + sr;
            int arow = row0 + r;
            if (arow < M)
                gload_lds16(&Asrc[(size_t)arow * K1 + k0 + ke], &sA[ch * 512]);
            gload_lds16(&B3[(size_t)(col0 + r) * 768 + s * 32 + ke], &sB[ch * 512]);
        }
        __syncthreads();                  // drains vmcnt (global_load_lds) too

        f16x8 af[4];
        #pragma unroll
        for (int f = 0; f < 4; ++f)
            af[f] = *(const f16x8*)&sA[(wm * 64 + f * 16 + fr) * 32 + kb];
        #pragma unroll
        for (int g = 0; g < 4; ++g) {
            f16x8 bf_ = *(const f16x8*)&sB[(wn * 64 + g * 16 + fr) * 32 + kb];
            #pragma unroll
            for (int f = 0; f < 4; ++f)
                acc[f][g] = __builtin_amdgcn_mfma_f32_16x16x32_f16(af[f], bf_, acc[f][g], 0, 0, 0);
        }
    }

    int rsub = (lane >> 4) * 4;
    #pragma unroll
    for (int f = 0; f < 4; ++f) {
        #pragma unroll
        for (int g = 0; g < 4; ++g) {
            int col = col0 + wn * 64 + g * 16 + fr;
            #pragma unroll
            for (int r = 0; r < 4; ++r) {
                int row = row0 + wm * 64 + f * 16 + rsub + r;
                if (row < M) C[(size_t)row * Nout + col] = (_Float16)acc[f][g][r];
            }
        }
    }
}

// ---------------------------------------------------------------------------
// XCD-sliced aggregation v4: fp16 H gather, 4 lanes x f16x8 per node (D=256,
// SLICE=32) / 2 lanes x f16x8 (D=128, SLICE=16). 8-deep unrolled edge loop
// (8 outstanding 16B gathers/wave). Per-XCD slice working set 3.2 MB -> L2-fit.
// fp32 accumulate; slice = bid&7 pins slice->XCD.
// MODE 0: relu, write fp16 hi/lo split; MODE 1: write fp32.
// ---------------------------------------------------------------------------
template <int D, int MODE>
__global__ __launch_bounds__(256) void aggregate_slice_k(const _Float16* __restrict__ H,
                                                         const float* __restrict__ bias,
                                                         const float* __restrict__ dinv,
                                                         const int* __restrict__ rp,
                                                         const int* __restrict__ cs,
                                                         _Float16* __restrict__ Yh,
                                                         _Float16* __restrict__ Yl,
                                                         float* __restrict__ Yf, int n) {
    constexpr int SLICE = (D == 256) ? 32 : 16;   // cols per slice
    constexpr int LPN = SLICE / 8;                // lanes per node (f16x8 each)
    constexpr int NPB = 256 / LPN;                // nodes per block

    int bid = blockIdx.x;
    int s = bid & 7;
    int v = (bid >> 3) * NPB + threadIdx.x / LPN;
    if (v >= n) return;
    int sub = threadIdx.x % LPN;
    int col = s * SLICE + sub * 8;

    float dv = dinv[v];
    float self = dv * dv;
    float acc[8];
    {
        f16x8 t0 = *(const f16x8*)&H[(size_t)v * D + col];
        #pragma unroll
        for (int i = 0; i < 8; ++i) acc[i] = self * (float)t0[i];
    }

    int beg = rp[v], end = rp[v + 1];
    int j = beg;
    for (; j + 8 <= end; j += 8) {
        int cc[8];
        #pragma unroll
        for (int u = 0; u < 8; ++u) cc[u] = cs[j + u];
        float nn[8];
        #pragma unroll
        for (int u = 0; u < 8; ++u) nn[u] = dv * dinv[cc[u]];
        f16x8 hv[8];
        #pragma unroll
        for (int u = 0; u < 8; ++u)
            hv[u] = *(const f16x8*)&H[(size_t)cc[u] * D + col];
        #pragma unroll
        for (int u = 0; u < 8; ++u)
            #pragma unroll
            for (int i = 0; i < 8; ++i)
                acc[i] += nn[u] * (float)hv[u][i];
    }
    for (; j < end; ++j) {
        int c = cs[j];
        float nm = dv * dinv[c];
        f16x8 a = *(const f16x8*)&H[(size_t)c * D + col];
        #pragma unroll
        for (int i = 0; i < 8; ++i) acc[i] += nm * (float)a[i];
    }

    float4 b0 = *(const float4*)&bias[col];
    float4 b1 = *(const float4*)&bias[col + 4];
    acc[0] += b0.x; acc[1] += b0.y; acc[2] += b0.z; acc[3] += b0.w;
    acc[4] += b1.x; acc[5] += b1.y; acc[6] += b1.z; acc[7] += b1.w;

    if constexpr (MODE == 0) {
        f16x8 hh, ll;
        #pragma unroll
        for (int i = 0; i < 8; ++i) {
            float o = fmaxf(acc[i], 0.0f);
            _Float16 h = (_Float16)o;
            hh[i] = h;
            ll[i] = (_Float16)(o - (float)h);
        }
        *(f16x8*)&Yh[(size_t)v * D + col] = hh;
        *(f16x8*)&Yl[(size_t)v * D + col] = ll;
    } else {
        *(float4*)&Yf[(size_t)v * D + col]     = make_float4(acc[0], acc[1], acc[2], acc[3]);
        *(float4*)&Yf[(size_t)v * D + col + 4] = make_float4(acc[4], acc[5], acc[6], acc[7]);
    }
}

// ---------------------------------------------------------------------------
extern "C" void kernel_launch(void* const* d_in, const int* in_sizes, int n_in,
                              void* d_out, int out_size, void* d_ws, size_t ws_size,
                              hipStream_t stream) {
    const float* qe  = (const float*)d_in[0];
    const float* obj = (const float*)d_in[1];
    const void*  edges = d_in[2];
    const float* W1 = (const float*)d_in[3];
    const float* b1 = (const float*)d_in[4];
    const float* W2 = (const float*)d_in[5];
    const float* b2 = (const float*)d_in[6];
    const float* W3 = (const float*)d_in[7];
    const float* b3 = (const float*)d_in[8];
    float* out = (float*)d_out;

    char* p = (char*)d_ws;
    _Float16* Xh   = (_Float16*)p; p += (size_t)NN * 256 * 2;   // 25.6 MB
    _Float16* Xl   = (_Float16*)p; p += (size_t)NN * 256 * 2;   // 25.6 MB
    _Float16* H    = (_Float16*)p; p += (size_t)NN * 256 * 2;   // 25.6 MB (fp16 now)
    _Float16* B3   = (_Float16*)p; p += (size_t)256 * 768 * 2;  // 0.4 MB
    int*   deg     = (int*)p;   p += (size_t)NN * 4;
    float* dinv    = (float*)p; p += (size_t)NN * 4;
    int*   rp      = (int*)p;   p += (size_t)(NN + 1) * 4;
    int*   cursor  = (int*)p;   p += (size_t)NN * 4;
    int*   col_s   = (int*)p;   p += (size_t)NE * 4;
    int*   flag    = (int*)p;   p += 4;

    zero_flag_k<<<1, 64, 0, stream>>>(flag);
    detect_k<<<4, 256, 0, stream>>>((const int*)edges, flag);
    hadamard_k<<<(NN * 64 + 255) / 256, 256, 0, stream>>>(
        (const float4*)qe, (const float4*)obj, Xh, Xl, NN * 64);
    init_k<<<(NN + 255) / 256, 256, 0, stream>>>(deg, cursor, NN);
    count_k<<<(NE + 255) / 256, 256, 0, stream>>>(edges, flag, deg, NE);
    dinv_k<<<(NN + 255) / 256, 256, 0, stream>>>(deg, dinv, NN);
    scan_k<<<1, 1024, 0, stream>>>(deg, rp, NN);
    scatter_k<<<(NE + 255) / 256, 256, 0, stream>>>(edges, flag, rp, cursor, col_s, NE);

    int mblk = (NN + 127) / 128;                 // 391
    int gemmBigGrid = ((mblk + 7) / 8) * 16;     // 800 (pair-swizzled, 2 col blocks)
    int agg256Grid = ((NN + 63) / 64) * 8;       // 6256  (64 nodes/block, 4 lanes/node)
    int agg128Grid = ((NN + 127) / 128) * 8;     // 3128  (128 nodes/block, 2 lanes/node)

    // Layer 1
    wconv3_k<<<256, 256, 0, stream>>>(W1, B3, 256);
    gemm_f16_k<2><<<gemmBigGrid, 256, 0, stream>>>(Xh, Xl, B3, H, NN, 256);
    aggregate_slice_k<256, 0><<<agg256Grid, 256, 0, stream>>>(H, b1, dinv, rp, col_s,
                                                              Xh, Xl, nullptr, NN);
    // Layer 2
    wconv3_k<<<256, 256, 0, stream>>>(W2, B3, 256);
    gemm_f16_k<2><<<gemmBigGrid, 256, 0, stream>>>(Xh, Xl, B3, H, NN, 256);
    aggregate_slice_k<256, 0><<<agg256Grid, 256, 0, stream>>>(H, b2, dinv, rp, col_s,
                                                              Xh, Xl, nullptr, NN);
    // Layer 3
    wconv3_k<<<128, 256, 0, stream>>>(W3, B3, 128);
    gemm_f16_k<1><<<mblk, 256, 0, stream>>>(Xh, Xl, B3, H, NN, 128);
    aggregate_slice_k<128, 1><<<agg128Grid, 256, 0, stream>>>(H, b3, dinv, rp, col_s,
                                                              nullptr, nullptr, out, NN);
}

// Round 7
// 508.975 us; speedup vs baseline: 1.2302x; 1.1605x over previous
//
#include <hip/hip_runtime.h>
#include <cstdint>
#include <cstddef>

#define NN 50000
#define NE 800000

typedef _Float16 f16x8 __attribute__((ext_vector_type(8)));
typedef _Float16 f16x4 __attribute__((ext_vector_type(4)));
typedef float f32x4 __attribute__((ext_vector_type(4)));

// ---------------------------------------------------------------------------
// Edge-index dtype robustness (int64 vs int32 canonicalization)
// ---------------------------------------------------------------------------
__device__ __forceinline__ int edge_at(const void* e, int is32, long long i) {
    return is32 ? ((const int*)e)[i] : (int)((const long long*)e)[i];
}

__global__ __launch_bounds__(64) void zero_flag_k(int* flag) {
    if (threadIdx.x == 0) *flag = 0;
}

__global__ __launch_bounds__(256) void detect_k(const int* __restrict__ w, int* __restrict__ flag) {
    int i = blockIdx.x * 256 + threadIdx.x;   // 0..1023
    if (i < 1024 && w[2 * i + 1] != 0) atomicOr(flag, 1);
}

// ---------------------------------------------------------------------------
// Hadamard: X0 = qe*obj, fp16 hi/lo split, written SLICE-MAJOR:
// X[panel][node][32], panel = col>>5.
// ---------------------------------------------------------------------------
__global__ __launch_bounds__(256) void hadamard_k(const float4* __restrict__ a,
                                                  const float4* __restrict__ b,
                                                  _Float16* __restrict__ Xh,
                                                  _Float16* __restrict__ Xl, int n4) {
    int i = blockIdx.x * 256 + threadIdx.x;
    if (i >= n4) return;
    float4 x = a[i], y = b[i];
    float v[4] = { x.x * y.x, x.y * y.y, x.z * y.z, x.w * y.w };
    f16x4 hh, ll;
    #pragma unroll
    for (int j = 0; j < 4; ++j) {
        _Float16 h = (_Float16)v[j];
        hh[j] = h;
        ll[j] = (_Float16)(v[j] - (float)h);
    }
    int row = i >> 6;              // 64 float4 per 256-col row
    int cq  = (i & 63) * 4;        // col base
    size_t off = ((size_t)(cq >> 5) * NN + row) * 32 + (cq & 31);
    *(f16x4*)&Xh[off] = hh;
    *(f16x4*)&Xl[off] = ll;
}

// ---------------------------------------------------------------------------
// Degree / CSR build
// ---------------------------------------------------------------------------
__global__ __launch_bounds__(256) void init_k(int* __restrict__ deg, int* __restrict__ cursor, int n) {
    int i = blockIdx.x * 256 + threadIdx.x;
    if (i < n) { deg[i] = 1; cursor[i] = 0; }   // self-loop
}

__global__ __launch_bounds__(256) void count_k(const void* __restrict__ edges,
                                               const int* __restrict__ flag,
                                               int* __restrict__ deg, int e) {
    int i = blockIdx.x * 256 + threadIdx.x;
    if (i < e) {
        int is32 = *flag;
        atomicAdd(&deg[edge_at(edges, is32, i)], 1);
    }
}

__global__ __launch_bounds__(256) void dinv_k(const int* __restrict__ deg, float* __restrict__ dinv, int n) {
    int i = blockIdx.x * 256 + threadIdx.x;
    if (i < n) dinv[i] = rsqrtf((float)deg[i]);
}

__global__ __launch_bounds__(1024) void scan_k(const int* __restrict__ deg, int* __restrict__ rp, int n) {
    __shared__ int s[1024];
    int t = threadIdx.x;
    int chunk = (n + 1023) / 1024;
    int lo = t * chunk;
    int hi = lo + chunk; if (hi > n) hi = n;
    int sum = 0;
    for (int i = lo; i < hi; ++i) sum += deg[i] - 1;
    s[t] = sum;
    __syncthreads();
    for (int off = 1; off < 1024; off <<= 1) {
        int val = (t >= off) ? s[t - off] : 0;
        __syncthreads();
        s[t] += val;
        __syncthreads();
    }
    int run = (t == 0) ? 0 : s[t - 1];
    for (int i = lo; i < hi; ++i) { rp[i] = run; run += deg[i] - 1; }
    if (t == 1023) rp[n] = s[1023];
}

// norm recomputed in the aggregate from dinv (L2-resident); CSR stores cols only.
__global__ __launch_bounds__(256) void scatter_k(const void* __restrict__ edges,
                                                 const int* __restrict__ flag,
                                                 const int* __restrict__ rp,
                                                 int* __restrict__ cursor,
                                                 int* __restrict__ col_s, int e) {
    int i = blockIdx.x * 256 + threadIdx.x;
    if (i < e) {
        int is32 = *flag;
        int r = edge_at(edges, is32, i);
        int c = edge_at(edges, is32, (long long)NE + i);
        int pos = rp[r] + atomicAdd(&cursor[r], 1);
        col_s[pos] = c;
    }
}

// ---------------------------------------------------------------------------
// W convert: W[K=256][Nout] fp32 -> B3 [Nout][768] fp16, layout [Wh | Wl | Wh]
// ---------------------------------------------------------------------------
__global__ __launch_bounds__(256) void wconv3_k(const float* __restrict__ W,
                                                _Float16* __restrict__ B3, int Nout) {
    int n = blockIdx.x;            // 0..Nout-1
    int k = threadIdx.x;           // 0..255
    float v = W[(size_t)k * Nout + n];
    _Float16 h = (_Float16)v;
    _Float16 l = (_Float16)(v - (float)h);
    B3[(size_t)n * 768 + k]       = h;
    B3[(size_t)n * 768 + 256 + k] = l;
    B3[(size_t)n * 768 + 512 + k] = h;
}

// ---------------------------------------------------------------------------
// Single-pass fp16 MFMA GEMM over virtual K=768 (m97 structure).
// A is SLICE-MAJOR: A[panel p][row][32] where p = k0/32. A-panel staging loads
// are globally contiguous 1KB chunks. Output C written SLICE-MAJOR with panel
// width SW (32 for D=256 layers, 16 for the D=128 layer), fp16.
// ---------------------------------------------------------------------------
__device__ __forceinline__ void gload_lds16(const void* g, void* l) {
    __builtin_amdgcn_global_load_lds(
        (const __attribute__((address_space(1))) void*)g,
        (__attribute__((address_space(3))) void*)l, 16, 0, 0);
}

template <int NBX, int SW>
__global__ __launch_bounds__(256) void gemm_f16_k(const _Float16* __restrict__ Ah,
                                                  const _Float16* __restrict__ Al,
                                                  const _Float16* __restrict__ B3,
                                                  _Float16* __restrict__ C,
                                                  int M, int Nout) {
    __shared__ alignas(16) _Float16 sA[128 * 32];   // linear: row r at r*32, 64B rows
    __shared__ alignas(16) _Float16 sB[128 * 32];
    constexpr int LG = (SW == 32) ? 5 : 4;
    int mblk = (M + 127) >> 7;

    int pair, xb;
    if (NBX == 2) {
        int b = blockIdx.x;
        pair = (b >> 4) * 8 + (b & 7);     // row-panel id; pinned to XCD (b&7)
        xb   = (b >> 3) & 1;
        if (pair >= mblk) return;
    } else {
        pair = blockIdx.x;
        xb = 0;
    }

    int tid = threadIdx.x;
    int row0 = pair * 128, col0 = xb * 128;
    int wid = tid >> 6, lane = tid & 63;
    int wm = wid >> 1, wn = wid & 1;
    int fr = lane & 15;
    int kb = (lane >> 4) * 8;       // k element base within 32

    int sr = lane >> 2;
    int ke = (lane & 3) * 8;

    f32x4 acc[4][4] = {};

    for (int s = 0; s < 24; ++s) {
        int seg = s >> 3;                 // 0: Ah, 1: Ah (L2-hot), 2: Al
        int p = s & 7;                    // A k-panel index
        const _Float16* Asrc = (seg == 2) ? Al : Ah;

        __syncthreads();                  // LDS reuse: prior reads done
        #pragma unroll
        for (int c = 0; c < 2; ++c) {
            int ch = wid * 2 + c;         // 0..7
            int r = ch * 16 + sr;
            int arow = row0 + r;
            if (arow < M)
                gload_lds16(&Asrc[((size_t)p * M + arow) * 32 + ke], &sA[ch * 512]);
            gload_lds16(&B3[(size_t)(col0 + r) * 768 + s * 32 + ke], &sB[ch * 512]);
        }
        __syncthreads();                  // drains vmcnt (global_load_lds) too

        f16x8 af[4];
        #pragma unroll
        for (int f = 0; f < 4; ++f)
            af[f] = *(const f16x8*)&sA[(wm * 64 + f * 16 + fr) * 32 + kb];
        #pragma unroll
        for (int g = 0; g < 4; ++g) {
            f16x8 bf_ = *(const f16x8*)&sB[(wn * 64 + g * 16 + fr) * 32 + kb];
            #pragma unroll
            for (int f = 0; f < 4; ++f)
                acc[f][g] = __builtin_amdgcn_mfma_f32_16x16x32_f16(af[f], bf_, acc[f][g], 0, 0, 0);
        }
    }

    int rsub = (lane >> 4) * 4;
    #pragma unroll
    for (int f = 0; f < 4; ++f) {
        #pragma unroll
        for (int g = 0; g < 4; ++g) {
            int col = col0 + wn * 64 + g * 16 + fr;
            #pragma unroll
            for (int r = 0; r < 4; ++r) {
                int row = row0 + wm * 64 + f * 16 + rsub + r;
                if (row < M)
                    C[((size_t)(col >> LG) * M + row) * SW + (col & (SW - 1))] =
                        (_Float16)acc[f][g][r];
            }
        }
    }
}

// ---------------------------------------------------------------------------
// XCD-sliced aggregation v5: slice-major fp16 H (panel = slice), so slice s's
// lines are 100% slice-s data -> per-XCD working set 3.2 MB (D=256) / 1.6 MB
// (D=128) -> L2-resident. slice = bid&7 pins slice->XCD. fp32 accumulate,
// 8-deep unrolled gather. MODE 0: relu, slice-major fp16 hi/lo out (next GEMM
// A panels). MODE 1: fp32 row-major out (d_out).
// ---------------------------------------------------------------------------
template <int D, int MODE>
__global__ __launch_bounds__(256) void aggregate_slice_k(const _Float16* __restrict__ H,
                                                         const float* __restrict__ bias,
                                                         const float* __restrict__ dinv,
                                                         const int* __restrict__ rp,
                                                         const int* __restrict__ cs,
                                                         _Float16* __restrict__ Yh,
                                                         _Float16* __restrict__ Yl,
                                                         float* __restrict__ Yf, int n) {
    constexpr int SLICE = (D == 256) ? 32 : 16;   // panel width
    constexpr int LPN = SLICE / 8;                // lanes per node (f16x8 each)
    constexpr int NPB = 256 / LPN;                // nodes per block

    int bid = blockIdx.x;
    int s = bid & 7;
    int v = (bid >> 3) * NPB + threadIdx.x / LPN;
    if (v >= n) return;
    int sub = threadIdx.x % LPN;
    int co = sub * 8;                             // within-panel col offset
    int col = s * SLICE + co;                     // global col (bias / out)

    const _Float16* Hs = H + (size_t)s * n * SLICE;   // this slice's panel

    float dv = dinv[v];
    float self = dv * dv;
    float acc[8];
    {
        f16x8 t0 = *(const f16x8*)&Hs[(size_t)v * SLICE + co];
        #pragma unroll
        for (int i = 0; i < 8; ++i) acc[i] = self * (float)t0[i];
    }

    int beg = rp[v], end = rp[v + 1];
    int j = beg;
    for (; j + 8 <= end; j += 8) {
        int cc[8];
        #pragma unroll
        for (int u = 0; u < 8; ++u) cc[u] = cs[j + u];
        float nn[8];
        #pragma unroll
        for (int u = 0; u < 8; ++u) nn[u] = dv * dinv[cc[u]];
        f16x8 hv[8];
        #pragma unroll
        for (int u = 0; u < 8; ++u)
            hv[u] = *(const f16x8*)&Hs[(size_t)cc[u] * SLICE + co];
        #pragma unroll
        for (int u = 0; u < 8; ++u)
            #pragma unroll
            for (int i = 0; i < 8; ++i)
                acc[i] += nn[u] * (float)hv[u][i];
    }
    for (; j < end; ++j) {
        int c = cs[j];
        float nm = dv * dinv[c];
        f16x8 a = *(const f16x8*)&Hs[(size_t)c * SLICE + co];
        #pragma unroll
        for (int i = 0; i < 8; ++i) acc[i] += nm * (float)a[i];
    }

    float4 b0 = *(const float4*)&bias[col];
    float4 b1 = *(const float4*)&bias[col + 4];
    acc[0] += b0.x; acc[1] += b0.y; acc[2] += b0.z; acc[3] += b0.w;
    acc[4] += b1.x; acc[5] += b1.y; acc[6] += b1.z; acc[7] += b1.w;

    if constexpr (MODE == 0) {
        f16x8 hh, ll;
        #pragma unroll
        for (int i = 0; i < 8; ++i) {
            float o = fmaxf(acc[i], 0.0f);
            _Float16 h = (_Float16)o;
            hh[i] = h;
            ll[i] = (_Float16)(o - (float)h);
        }
        size_t off = ((size_t)s * n + v) * SLICE + co;   // slice-major out
        *(f16x8*)&Yh[off] = hh;
        *(f16x8*)&Yl[off] = ll;
    } else {
        *(float4*)&Yf[(size_t)v * D + col]     = make_float4(acc[0], acc[1], acc[2], acc[3]);
        *(float4*)&Yf[(size_t)v * D + col + 4] = make_float4(acc[4], acc[5], acc[6], acc[7]);
    }
}

// ---------------------------------------------------------------------------
extern "C" void kernel_launch(void* const* d_in, const int* in_sizes, int n_in,
                              void* d_out, int out_size, void* d_ws, size_t ws_size,
                              hipStream_t stream) {
    const float* qe  = (const float*)d_in[0];
    const float* obj = (const float*)d_in[1];
    const void*  edges = d_in[2];
    const float* W1 = (const float*)d_in[3];
    const float* b1 = (const float*)d_in[4];
    const float* W2 = (const float*)d_in[5];
    const float* b2 = (const float*)d_in[6];
    const float* W3 = (const float*)d_in[7];
    const float* b3 = (const float*)d_in[8];
    float* out = (float*)d_out;

    char* p = (char*)d_ws;
    _Float16* Xh   = (_Float16*)p; p += (size_t)NN * 256 * 2;   // 25.6 MB (slice-major)
    _Float16* Xl   = (_Float16*)p; p += (size_t)NN * 256 * 2;   // 25.6 MB (slice-major)
    _Float16* H    = (_Float16*)p; p += (size_t)NN * 256 * 2;   // 25.6 MB (slice-major)
    _Float16* B3   = (_Float16*)p; p += (size_t)256 * 768 * 2;  // 0.4 MB
    int*   deg     = (int*)p;   p += (size_t)NN * 4;
    float* dinv    = (float*)p; p += (size_t)NN * 4;
    int*   rp      = (int*)p;   p += (size_t)(NN + 1) * 4;
    int*   cursor  = (int*)p;   p += (size_t)NN * 4;
    int*   col_s   = (int*)p;   p += (size_t)NE * 4;
    int*   flag    = (int*)p;   p += 4;

    zero_flag_k<<<1, 64, 0, stream>>>(flag);
    detect_k<<<4, 256, 0, stream>>>((const int*)edges, flag);
    hadamard_k<<<(NN * 64 + 255) / 256, 256, 0, stream>>>(
        (const float4*)qe, (const float4*)obj, Xh, Xl, NN * 64);
    init_k<<<(NN + 255) / 256, 256, 0, stream>>>(deg, cursor, NN);
    count_k<<<(NE + 255) / 256, 256, 0, stream>>>(edges, flag, deg, NE);
    dinv_k<<<(NN + 255) / 256, 256, 0, stream>>>(deg, dinv, NN);
    scan_k<<<1, 1024, 0, stream>>>(deg, rp, NN);
    scatter_k<<<(NE + 255) / 256, 256, 0, stream>>>(edges, flag, rp, cursor, col_s, NE);

    int mblk = (NN + 127) / 128;                 // 391
    int gemmBigGrid = ((mblk + 7) / 8) * 16;     // 800 (pair-swizzled, 2 col blocks)
    int agg256Grid = ((NN + 63) / 64) * 8;       // 6256  (64 nodes/block, 4 lanes/node)
    int agg128Grid = ((NN + 127) / 128) * 8;     // 3128  (128 nodes/block, 2 lanes/node)

    // Layer 1
    wconv3_k<<<256, 256, 0, stream>>>(W1, B3, 256);
    gemm_f16_k<2, 32><<<gemmBigGrid, 256, 0, stream>>>(Xh, Xl, B3, H, NN, 256);
    aggregate_slice_k<256, 0><<<agg256Grid, 256, 0, stream>>>(H, b1, dinv, rp, col_s,
                                                              Xh, Xl, nullptr, NN);
    // Layer 2
    wconv3_k<<<256, 256, 0, stream>>>(W2, B3, 256);
    gemm_f16_k<2, 32><<<gemmBigGrid, 256, 0, stream>>>(Xh, Xl, B3, H, NN, 256);
    aggregate_slice_k<256, 0><<<agg256Grid, 256, 0, stream>>>(H, b2, dinv, rp, col_s,
                                                              Xh, Xl, nullptr, NN);
    // Layer 3
    wconv3_k<<<128, 256, 0, stream>>>(W3, B3, 128);
    gemm_f16_k<1, 16><<<mblk, 256, 0, stream>>>(Xh, Xl, B3, H, NN, 128);
    aggregate_slice_k<128, 1><<<agg128Grid, 256, 0, stream>>>(H, b3, dinv, rp, col_s,
                                                              nullptr, nullptr, out, NN);
}